// Round 6
// baseline (698.132 us; speedup 1.0000x reference)
//
#include <hip/hip_runtime.h>
#include <stdint.h>

// ---------------------------------------------------------------------------
// GAU forward on MI355X (gfx950), bf16 MFMA everywhere.
//   hid|qk = silu(x@[Wh|Wqk]+b) -> vT [2048][8192], gate [8192][2048],
//                                  q,k bf16 [8192][256] (cols 200..255 zero)
//   attn = relu(q@kT / 32)^2    bf16 (full [8192][8192] if ws allows, else 2 stripes)
//   out2 = (attn@v) * gate      bf16 [8192][2048]   (k_pv 128x256, XCD swizzle)
//   y    = (out2@Wo + bo) * x   fp32 [8192][1024]
//
// R6: (1) k_attn: K padded to 256, TWO BK=128 slabs (64KB LDS, 2 barrier-pairs
// total vs 7) with XOR-swizzled LDS chunks (stride-128 rows all alias bank 0
// otherwise); (2) hid_qk epilogue: vT/gate bounced through LDS -> 128B-line
// stores (was 8B/2B scatters); (3) k_pv epilogue: LDS bounce + 16B gate
// loads/stores (was 2B scalars). k_pv K-loop untouched (m97 plateau, 890 TF).
// ---------------------------------------------------------------------------

typedef __bf16 bf16x8 __attribute__((ext_vector_type(8)));
typedef float f32x4 __attribute__((ext_vector_type(4)));

__device__ __forceinline__ uint16_t f2bf(float f) {
  uint32_t u = __builtin_bit_cast(uint32_t, f);
  u += 0x7fffu + ((u >> 16) & 1u);   // RNE; inputs are finite
  return (uint16_t)(u >> 16);
}
__device__ __forceinline__ float silu_f(float s) {
  return s / (1.f + __expf(-s));
}

__device__ __forceinline__ void gload16(const void* g, void* l) {
  __builtin_amdgcn_global_load_lds(
      (__attribute__((address_space(1))) void*)const_cast<void*>(g),
      (__attribute__((address_space(3))) void*)l, 16, 0, 0);
}

// ---------------- elementwise prep ----------------

__global__ void cast_to_bf16(const float* __restrict__ in, uint16_t* __restrict__ out, int n4) {
  int i = blockIdx.x * blockDim.x + threadIdx.x;
  if (i < n4) {
    float4 f = ((const float4*)in)[i];
    ushort4 o;
    o.x = f2bf(f.x); o.y = f2bf(f.y); o.z = f2bf(f.z); o.w = f2bf(f.w);
    ((ushort4*)out)[i] = o;
  }
}

// out[c][r] = (c < C) ? (bf16)in[r][c] : 0   ; out is [Cp][R]
__global__ void transpose_cast_pad(const float* __restrict__ in, uint16_t* __restrict__ out,
                                   int R, int C, int Cp) {
  __shared__ float tile[32][33];
  int cb = blockIdx.x * 32;
  int rb = blockIdx.y * 32;
  int tx = threadIdx.x;
  int ty = threadIdx.y;
#pragma unroll
  for (int i = 0; i < 4; ++i) {
    int r = rb + ty + i * 8;
    int c = cb + tx;
    tile[ty + i * 8][tx] = (c < C) ? in[(size_t)r * C + c] : 0.f;
  }
  __syncthreads();
#pragma unroll
  for (int i = 0; i < 4; ++i) {
    int c = cb + ty + i * 8;
    if (c < Cp) out[(size_t)c * R + rb + tx] = f2bf(tile[tx][ty + i * 8]);
  }
}

// ---------------- params ----------------

struct EpiParams {
  const float* bias;
  const float* bias2;
  const float* g0;
  const float* b0;
  const float* g1;
  const float* b1;
  const uint16_t* gate;
  const float* x;
  uint16_t* o16a;
  uint16_t* o16b;
  uint16_t* oq;
  uint16_t* ok;
  float* o32;
};

// ---------------------------------------------------------------------------
// k_hidqk: C = xb[8192,1024] @ [WhT;WqkT][4352,1024]^T, 128x128 tile.
// Per-block epilogue specialization (n0 block-uniform): vT / gate / qk.
// vT & gate bounce through per-wave LDS arena -> 128B-line coalesced stores.
// ---------------------------------------------------------------------------
__global__ __launch_bounds__(256) void k_hidqk(
    const uint16_t* __restrict__ A, const uint16_t* __restrict__ Bt, EpiParams p) {
  __shared__ __align__(16) uint16_t SH[128 * 64];   // As | Bs, 16 KB
  uint16_t* As = SH;
  uint16_t* Bs = SH + 4096;

  const int tid = threadIdx.x;
  const int lane = tid & 63;
  const int wave = tid >> 6;
  const int wr = (wave >> 1) * 64;
  const int wc = (wave & 1) * 64;
  const int m0 = blockIdx.y * 128;
  const int n0 = blockIdx.x * 128;
  const int lda = 1024, ldb = 1024, K = 1024;

  f32x4 acc[4][4] = {};

  const int r0 = tid >> 2;
  const int q8 = (tid & 3) * 8;
  const uint16_t* gA0 = A + (size_t)(m0 + r0) * lda + q8;
  const uint16_t* gA1 = A + (size_t)(m0 + 64 + r0) * lda + q8;
  const uint16_t* gB0 = Bt + (size_t)(n0 + r0) * ldb + q8;
  const uint16_t* gB1 = Bt + (size_t)(n0 + 64 + r0) * ldb + q8;
  uint16_t* lA0 = As + wave * 512;
  uint16_t* lA1 = As + 2048 + wave * 512;
  uint16_t* lB0 = Bs + wave * 512;
  uint16_t* lB1 = Bs + 2048 + wave * 512;

  const int fr = lane & 15;
  const int rg = lane >> 4;
  const int kq = rg * 8;

  for (int k0 = 0; k0 < K; k0 += 32) {
    __syncthreads();
    gload16(gA0 + k0, lA0);
    gload16(gA1 + k0, lA1);
    gload16(gB0 + k0, lB0);
    gload16(gB1 + k0, lB1);
    __syncthreads();

    bf16x8 a[4], b[4];
#pragma unroll
    for (int i = 0; i < 4; ++i)
      a[i] = *(const bf16x8*)(As + (wr + i * 16 + fr) * 32 + kq);
#pragma unroll
    for (int j = 0; j < 4; ++j)
      b[j] = *(const bf16x8*)(Bs + (wc + j * 16 + fr) * 32 + kq);
#pragma unroll
    for (int i = 0; i < 4; ++i)
#pragma unroll
      for (int j = 0; j < 4; ++j)
        acc[i][j] = __builtin_amdgcn_mfma_f32_16x16x32_bf16(a[i], b[j], acc[i][j], 0, 0, 0);
  }

  // C/D layout: col = lane&15, row = rg*4 + reg   [m89-verified]
  if (n0 < 2048) {
    // vT (transposed store). Arena [16 n-rows][64 m + pad] stride 72.
    __syncthreads();
    uint16_t* ar = SH + wave * 2048;
    const int lrow = lane >> 3;
    const int mc = (lane & 7) * 8;
#pragma unroll
    for (int j = 0; j < 4; ++j) {
      const float bc = p.bias[n0 + wc + j * 16 + fr];
#pragma unroll
      for (int i = 0; i < 4; ++i)
#pragma unroll
        for (int r = 0; r < 4; ++r)
          ar[fr * 72 + i * 16 + rg * 4 + r] = f2bf(silu_f(acc[i][j][r] + bc));
#pragma unroll
      for (int rr = 0; rr < 2; ++rr) {
        bf16x8 v = *(const bf16x8*)(ar + (rr * 8 + lrow) * 72 + mc);
        *(bf16x8*)(p.o16a + (size_t)(n0 + wc + j * 16 + rr * 8 + lrow) * 8192 + m0 + wr + mc) = v;
      }
    }
  } else if (n0 < 4096) {
    // gate. Arena [16 m-rows][64 n + pad] stride 72.
    __syncthreads();
    uint16_t* ar = SH + wave * 2048;
    const int lrow = lane >> 3;
    const int nc = (lane & 7) * 8;
    float bc[4];
#pragma unroll
    for (int j = 0; j < 4; ++j) bc[j] = p.bias[n0 + wc + j * 16 + fr];
#pragma unroll
    for (int i = 0; i < 4; ++i) {
#pragma unroll
      for (int j = 0; j < 4; ++j)
#pragma unroll
        for (int r = 0; r < 4; ++r)
          ar[(rg * 4 + r) * 72 + j * 16 + fr] = f2bf(silu_f(acc[i][j][r] + bc[j]));
#pragma unroll
      for (int rr = 0; rr < 2; ++rr) {
        bf16x8 v = *(const bf16x8*)(ar + (rr * 8 + lrow) * 72 + nc);
        *(bf16x8*)(p.o16b + (size_t)(m0 + wr + i * 16 + rr * 8 + lrow) * 2048 + (n0 - 2048) + wc + nc) = v;
      }
    }
  } else {
    // q,k: stride 256, cols 200..255 forced zero.
#pragma unroll
    for (int i = 0; i < 4; ++i) {
#pragma unroll
      for (int j = 0; j < 4; ++j) {
        const int row = m0 + wr + i * 16 + rg * 4;
        const int qc = n0 + wc + j * 16 + fr - 4096;   // 0..255
#pragma unroll
        for (int r = 0; r < 4; ++r) {
          float qv = 0.f, kv = 0.f;
          if (qc < 200) {
            float s = silu_f(acc[i][j][r] + p.bias2[qc]);
            qv = s * p.g0[qc] + p.b0[qc];
            kv = s * p.g1[qc] + p.b1[qc];
          }
          p.oq[(size_t)(row + r) * 256 + qc] = f2bf(qv);
          p.ok[(size_t)(row + r) * 256 + qc] = f2bf(kv);
        }
      }
    }
  }
}

// ---------------------------------------------------------------------------
// k_attn: attn = relu(q@kT/32)^2. K=256 (padded), two BK=128 slabs staged
// whole -> 2 barrier-pairs total. LDS rows stride 128 elems would alias
// bank 0 for every row, so chunks are XOR-swizzled: phys = log ^ (row&15).
// Coalesced bounce epilogue (R5-verified pattern), arena reuses As.
// ---------------------------------------------------------------------------
__global__ __launch_bounds__(256) void k_attn(
    const uint16_t* __restrict__ Q,
    const uint16_t* __restrict__ Kt,
    uint16_t* __restrict__ attn) {
  __shared__ __align__(16) uint16_t As[128 * 128];   // 32 KB
  __shared__ __align__(16) uint16_t Bs[128 * 128];   // 32 KB

  const int tid = threadIdx.x;
  const int lane = tid & 63;
  const int wave = tid >> 6;
  const int wr = (wave >> 1) * 64;
  const int wc = (wave & 1) * 64;
  const int m0 = blockIdx.y * 128;
  const int n0 = blockIdx.x * 128;
  const int fr = lane & 15;
  const int rg = lane >> 4;

  f32x4 acc[4][4] = {};

  for (int ko = 0; ko < 256; ko += 128) {
    __syncthreads();
#pragma unroll
    for (int t = 0; t < 8; ++t) {
      const int s = t * 4 + wave;              // wave-instr slot 0..31
      const int row = s * 4 + rg;              // 0..127
      const int log8 = fr ^ (row & 15);        // logical 16B chunk in row
      gload16(Q + (size_t)(m0 + row) * 256 + ko + log8 * 8, As + s * 512);
      gload16(Kt + (size_t)(n0 + row) * 256 + ko + log8 * 8, Bs + s * 512);
    }
    __syncthreads();

#pragma unroll
    for (int kc = 0; kc < 4; ++kc) {
      bf16x8 a[4], b[4];
#pragma unroll
      for (int i = 0; i < 4; ++i)
        a[i] = *(const bf16x8*)(As + (wr + i * 16 + fr) * 128 + (((kc * 4 + rg) ^ fr) * 8));
#pragma unroll
      for (int j = 0; j < 4; ++j)
        b[j] = *(const bf16x8*)(Bs + (wc + j * 16 + fr) * 128 + (((kc * 4 + rg) ^ fr) * 8));
#pragma unroll
      for (int i = 0; i < 4; ++i)
#pragma unroll
        for (int j = 0; j < 4; ++j)
          acc[i][j] = __builtin_amdgcn_mfma_f32_16x16x32_bf16(a[i], b[j], acc[i][j], 0, 0, 0);
    }
  }

  __syncthreads();                              // all LDS reads drained; reuse As
  uint16_t* sl0 = As + wave * 2304;             // 2 x 1152-elem buffers per wave
#pragma unroll
  for (int i = 0; i < 4; ++i) {
    uint16_t* sl = sl0 + (i & 1) * 1152;
#pragma unroll
    for (int j = 0; j < 4; ++j)
#pragma unroll
      for (int r = 0; r < 4; ++r) {
        float s = fmaxf(acc[i][j][r] * 0.03125f, 0.f);
        sl[(rg * 4 + r) * 72 + j * 16 + fr] = f2bf(s * s);
      }
    const int row = lane >> 2;
    const int c0 = (lane & 3) * 16;
    bf16x8 v0 = *(const bf16x8*)(sl + row * 72 + c0);
    bf16x8 v1 = *(const bf16x8*)(sl + row * 72 + c0 + 8);
    uint16_t* dst = attn + (size_t)(m0 + wr + i * 16 + row) * 8192 + (n0 + wc + c0);
    *(bf16x8*)(dst) = v0;
    *(bf16x8*)(dst + 8) = v1;
  }
}

// ---------------------------------------------------------------------------
// k_pv: out2 = (attn@v)*gate. 128(M) x 256(N), 512 thr, XCD swizzle.
// K-loop frozen (m97 plateau). Epilogue: LDS bounce, 16B gate loads + stores.
// ---------------------------------------------------------------------------
__global__ __launch_bounds__(512) void k_pv(
    const uint16_t* __restrict__ A, int lda,
    const uint16_t* __restrict__ Bt, int ldb,
    int K, int nx, EpiParams p) {
  __shared__ __align__(16) uint16_t SH[(128 + 256) * 32];   // As | Bs, 24 KB
  uint16_t* As = SH;
  uint16_t* Bs = SH + 4096;

  const int id = blockIdx.x;
  const int bx = (id >> 3) % nx;
  const int by = (id & 7) + 8 * (id / (8 * nx));
  const int m0 = by * 128;
  const int n0 = bx * 256;

  const int tid = threadIdx.x;
  const int lane = tid & 63;
  const int wave = tid >> 6;
  const int wr = (wave & 1) * 64;
  const int wc = (wave >> 1) * 64;

  f32x4 acc[4][4] = {};

  const int r0 = tid >> 2;
  const int q8 = (tid & 3) * 8;
  const uint16_t* gA  = A  + (size_t)(m0 + r0) * lda + q8;
  const uint16_t* gB0 = Bt + (size_t)(n0 + r0) * ldb + q8;
  const uint16_t* gB1 = Bt + (size_t)(n0 + 128 + r0) * ldb + q8;
  uint16_t* lA  = As + wave * 512;
  uint16_t* lB0 = Bs + wave * 512;
  uint16_t* lB1 = Bs + 4096 + wave * 512;

  const int fr = lane & 15;
  const int rg = lane >> 4;
  const int kq = rg * 8;

  for (int k0 = 0; k0 < K; k0 += 32) {
    __syncthreads();
    gload16(gA + k0, lA);
    gload16(gB0 + k0, lB0);
    gload16(gB1 + k0, lB1);
    __syncthreads();

    bf16x8 a[4], b[4];
#pragma unroll
    for (int i = 0; i < 4; ++i)
      a[i] = *(const bf16x8*)(As + (wr + i * 16 + fr) * 32 + kq);
#pragma unroll
    for (int j = 0; j < 4; ++j)
      b[j] = *(const bf16x8*)(Bs + (wc + j * 16 + fr) * 32 + kq);
#pragma unroll
    for (int i = 0; i < 4; ++i)
#pragma unroll
      for (int j = 0; j < 4; ++j)
        acc[i][j] = __builtin_amdgcn_mfma_f32_16x16x32_bf16(a[i], b[j], acc[i][j], 0, 0, 0);
  }

  __syncthreads();                         // reuse SH as arena
  uint16_t* ar = SH + wave * 1536;         // [16][72], 1152 used
  const int lrow = lane >> 3;
  const int nc = (lane & 7) * 8;
#pragma unroll
  for (int i = 0; i < 4; ++i) {
#pragma unroll
    for (int j = 0; j < 4; ++j)
#pragma unroll
      for (int r = 0; r < 4; ++r)
        ar[(rg * 4 + r) * 72 + j * 16 + fr] = f2bf(acc[i][j][r]);
#pragma unroll
    for (int rr = 0; rr < 2; ++rr) {
      const size_t base = (size_t)(m0 + wr + i * 16 + rr * 8 + lrow) * 2048 + n0 + wc + nc;
      bf16x8 v = *(const bf16x8*)(ar + (rr * 8 + lrow) * 72 + nc);
      bf16x8 g = *(const bf16x8*)(p.gate + base);
      bf16x8 o;
#pragma unroll
      for (int e = 0; e < 8; ++e) o[e] = (__bf16)((float)v[e] * (float)g[e]);
      *(bf16x8*)(p.o16a + base) = o;
    }
  }
}

// ---------------------------------------------------------------------------
// k_final: y = (out2g@WoT^T + bo) * x, fp32 out. 128x128, K=2048.
// ---------------------------------------------------------------------------
__global__ __launch_bounds__(256) void k_final(
    const uint16_t* __restrict__ A,
    const uint16_t* __restrict__ Bt, EpiParams p) {
  __shared__ __align__(16) uint16_t As[128 * 32];
  __shared__ __align__(16) uint16_t Bs[128 * 32];

  const int tid = threadIdx.x;
  const int lane = tid & 63;
  const int wave = tid >> 6;
  const int wr = (wave >> 1) * 64;
  const int wc = (wave & 1) * 64;
  const int m0 = blockIdx.y * 128;
  const int n0 = blockIdx.x * 128;
  const int lda = 2048, ldb = 2048, K = 2048;

  f32x4 acc[4][4] = {};

  const int r0 = tid >> 2;
  const int q8 = (tid & 3) * 8;
  const uint16_t* gA0 = A + (size_t)(m0 + r0) * lda + q8;
  const uint16_t* gA1 = A + (size_t)(m0 + 64 + r0) * lda + q8;
  const uint16_t* gB0 = Bt + (size_t)(n0 + r0) * ldb + q8;
  const uint16_t* gB1 = Bt + (size_t)(n0 + 64 + r0) * ldb + q8;
  uint16_t* lA0 = As + wave * 512;
  uint16_t* lA1 = As + 2048 + wave * 512;
  uint16_t* lB0 = Bs + wave * 512;
  uint16_t* lB1 = Bs + 2048 + wave * 512;

  const int fr = lane & 15;
  const int kq = (lane >> 4) * 8;

  for (int k0 = 0; k0 < K; k0 += 32) {
    __syncthreads();
    gload16(gA0 + k0, lA0);
    gload16(gA1 + k0, lA1);
    gload16(gB0 + k0, lB0);
    gload16(gB1 + k0, lB1);
    __syncthreads();

    bf16x8 a[4], b[4];
#pragma unroll
    for (int i = 0; i < 4; ++i)
      a[i] = *(const bf16x8*)(As + (wr + i * 16 + fr) * 32 + kq);
#pragma unroll
    for (int j = 0; j < 4; ++j)
      b[j] = *(const bf16x8*)(Bs + (wc + j * 16 + fr) * 32 + kq);
#pragma unroll
    for (int i = 0; i < 4; ++i)
#pragma unroll
      for (int j = 0; j < 4; ++j)
        acc[i][j] = __builtin_amdgcn_mfma_f32_16x16x32_bf16(a[i], b[j], acc[i][j], 0, 0, 0);
  }

#pragma unroll
  for (int i = 0; i < 4; ++i) {
#pragma unroll
    for (int j = 0; j < 4; ++j) {
      const int row = m0 + wr + i * 16 + (lane >> 4) * 4;
      const int col = n0 + wc + j * 16 + fr;
      const float bc = p.bias[col];
#pragma unroll
      for (int r = 0; r < 4; ++r) {
        size_t idx = (size_t)(row + r) * 1024 + col;
        p.o32[idx] = (acc[i][j][r] + bc) * p.x[idx];
      }
    }
  }
}

// ---------------- launch ----------------

extern "C" void kernel_launch(void* const* d_in, const int* in_sizes, int n_in,
                              void* d_out, int out_size, void* d_ws, size_t ws_size,
                              hipStream_t stream) {
  const float* x        = (const float*)d_in[0];
  const float* W_hidden = (const float*)d_in[1];
  const float* b_hidden = (const float*)d_in[2];
  const float* W_qk     = (const float*)d_in[3];
  const float* b_qk     = (const float*)d_in[4];
  const float* gamma    = (const float*)d_in[5];
  const float* beta     = (const float*)d_in[6];
  const float* W_out    = (const float*)d_in[7];
  const float* b_out    = (const float*)d_in[8];
  float* out = (float*)d_out;

  // fullM: region0 = attn 128 MB (aliases xb/WhT/WqkT) + tail 108 MB = 236 MB.
  const bool fullM = ws_size >= (236ull << 20);
  const size_t region0 = fullM ? (128ull << 20) : (64ull << 20);

  char* base = (char*)d_ws;
  uint16_t* xb    = (uint16_t*)(base);                         // 16 MB  [8192][1024]
  uint16_t* WhT   = (uint16_t*)(base + (16ull << 20));         //  8 MB  [4096][1024]
  uint16_t* WqkT  = (uint16_t*)(base + (24ull << 20));         // .5 MB  [256][1024]
  uint16_t* attnB = (uint16_t*)(base);                         // 64/128 MB
  char* tail = base + region0;
  uint16_t* WoT   = (uint16_t*)(tail);                         //  4 MB  [1024][2048]
  uint16_t* q     = (uint16_t*)(tail + (4ull << 20));          //  4 MB  [8192][256]
  uint16_t* kk    = (uint16_t*)(tail + (8ull << 20));          //  4 MB  [8192][256]
  uint16_t* vT    = (uint16_t*)(tail + (12ull << 20));         // 32 MB  [2048][8192]
  uint16_t* gate  = (uint16_t*)(tail + (44ull << 20));         // 32 MB  [8192][2048]
  uint16_t* out2g = (uint16_t*)(tail + (76ull << 20));         // 32 MB  [8192][2048]
  (void)in_sizes; (void)n_in; (void)out_size;

  // prep
  cast_to_bf16<<<(8192 * 1024 / 4) / 256, 256, 0, stream>>>(x, xb, 8192 * 1024 / 4);
  transpose_cast_pad<<<dim3(4096 / 32, 1024 / 32), dim3(32, 8), 0, stream>>>(W_hidden, WhT, 1024, 4096, 4096);
  transpose_cast_pad<<<dim3(256 / 32, 1024 / 32), dim3(32, 8), 0, stream>>>(W_qk, WqkT, 1024, 200, 256);
  transpose_cast_pad<<<dim3(1024 / 32, 2048 / 32), dim3(32, 8), 0, stream>>>(W_out, WoT, 2048, 1024, 1024);

  // fused hid + qk   (N = 4096 + 256 = 4352)
  {
    EpiParams p{};
    p.bias = b_hidden; p.bias2 = b_qk;
    p.g0 = gamma; p.b0 = beta; p.g1 = gamma + 200; p.b1 = beta + 200;
    p.o16a = vT; p.o16b = gate; p.oq = q; p.ok = kk;
    k_hidqk<<<dim3(34, 64), 256, 0, stream>>>(xb, WhT, p);
  }

  if (fullM) {
    k_attn<<<dim3(64, 64), 256, 0, stream>>>(q, kk, attnB);
    {
      EpiParams p{};
      p.gate = gate; p.o16a = out2g;
      k_pv<<<dim3(8 * 64), 512, 0, stream>>>(attnB, 8192, vT, 8192, 8192, 8, p);
    }
  } else {
    for (int s = 0; s < 2; ++s) {
      k_attn<<<dim3(64, 32), 256, 0, stream>>>(q + (size_t)s * 4096 * 256, kk, attnB);
      {
        EpiParams p{};
        p.gate = gate + (size_t)s * 4096 * 2048;
        p.o16a = out2g + (size_t)s * 4096 * 2048;
        k_pv<<<dim3(8 * 32), 512, 0, stream>>>(attnB, 8192, vT, 8192, 8192, 8, p);
      }
    }
  }

  // y = (out2g@Wo + bo) * x
  {
    EpiParams p{};
    p.bias = b_out; p.x = x; p.o32 = out;
    k_final<<<dim3(8, 64), 256, 0, stream>>>(out2g, WoT, p);
  }
}

// Round 7
// 641.044 us; speedup vs baseline: 1.0891x; 1.0891x over previous
//
#include <hip/hip_runtime.h>
#include <stdint.h>

// ---------------------------------------------------------------------------
// GAU forward on MI355X (gfx950), bf16 MFMA everywhere.
//   hid|qk = silu(x@[Wh|Wqk]+b) -> vT [2048][8192], gate [8192][2048],
//                                  q,k bf16 [8192][224] (cols 200..223 zero)
//   attn = relu(q@kT / 32)^2    bf16 (full [8192][8192] if ws allows, else 2 stripes)
//   out2 = (attn@v) * gate      bf16 [8192][2048]   (k_pv 128x256, XCD swizzle)
//   y    = (out2@Wo + bo) * x   fp32 [8192][1024]
//
// R7: revert k_attn to R5 structure (m97-style K=224 loop, ~34 KB LDS ->
// 4 blocks/CU). R6's 64KB-slab k_attn dropped to 2 blocks/CU and regressed
// ~40 us (same shape as learn_hip m132's BK=128 loss). Keep R6's k_pv
// bounce epilogue (measured -11 us, WRITE_SIZE now ideal 32.8 MB) and
// hidqk bounce epilogues. k_pv K-loop frozen at the m97 plateau (~920 TF).
// ---------------------------------------------------------------------------

typedef __bf16 bf16x8 __attribute__((ext_vector_type(8)));
typedef float f32x4 __attribute__((ext_vector_type(4)));

__device__ __forceinline__ uint16_t f2bf(float f) {
  uint32_t u = __builtin_bit_cast(uint32_t, f);
  u += 0x7fffu + ((u >> 16) & 1u);   // RNE; inputs are finite
  return (uint16_t)(u >> 16);
}
__device__ __forceinline__ float silu_f(float s) {
  return s / (1.f + __expf(-s));
}

__device__ __forceinline__ void gload16(const void* g, void* l) {
  __builtin_amdgcn_global_load_lds(
      (__attribute__((address_space(1))) void*)const_cast<void*>(g),
      (__attribute__((address_space(3))) void*)l, 16, 0, 0);
}

// ---------------- elementwise prep ----------------

__global__ void cast_to_bf16(const float* __restrict__ in, uint16_t* __restrict__ out, int n4) {
  int i = blockIdx.x * blockDim.x + threadIdx.x;
  if (i < n4) {
    float4 f = ((const float4*)in)[i];
    ushort4 o;
    o.x = f2bf(f.x); o.y = f2bf(f.y); o.z = f2bf(f.z); o.w = f2bf(f.w);
    ((ushort4*)out)[i] = o;
  }
}

// out[c][r] = (c < C) ? (bf16)in[r][c] : 0   ; out is [Cp][R]
__global__ void transpose_cast_pad(const float* __restrict__ in, uint16_t* __restrict__ out,
                                   int R, int C, int Cp) {
  __shared__ float tile[32][33];
  int cb = blockIdx.x * 32;
  int rb = blockIdx.y * 32;
  int tx = threadIdx.x;
  int ty = threadIdx.y;
#pragma unroll
  for (int i = 0; i < 4; ++i) {
    int r = rb + ty + i * 8;
    int c = cb + tx;
    tile[ty + i * 8][tx] = (c < C) ? in[(size_t)r * C + c] : 0.f;
  }
  __syncthreads();
#pragma unroll
  for (int i = 0; i < 4; ++i) {
    int c = cb + ty + i * 8;
    if (c < Cp) out[(size_t)c * R + rb + tx] = f2bf(tile[tx][ty + i * 8]);
  }
}

// ---------------- params ----------------

struct EpiParams {
  const float* bias;
  const float* bias2;
  const float* g0;
  const float* b0;
  const float* g1;
  const float* b1;
  const uint16_t* gate;
  const float* x;
  uint16_t* o16a;
  uint16_t* o16b;
  uint16_t* oq;
  uint16_t* ok;
  float* o32;
};

// ---------------------------------------------------------------------------
// k_hidqk: C = xb[8192,1024] @ [WhT;WqkT][4352,1024]^T, 128x128 tile.
// Per-block epilogue specialization (n0 block-uniform): vT / gate / qk.
// vT & gate bounce through per-wave LDS arena -> 128B-line coalesced stores.
// ---------------------------------------------------------------------------
__global__ __launch_bounds__(256) void k_hidqk(
    const uint16_t* __restrict__ A, const uint16_t* __restrict__ Bt, EpiParams p) {
  __shared__ __align__(16) uint16_t SH[128 * 64];   // As | Bs, 16 KB
  uint16_t* As = SH;
  uint16_t* Bs = SH + 4096;

  const int tid = threadIdx.x;
  const int lane = tid & 63;
  const int wave = tid >> 6;
  const int wr = (wave >> 1) * 64;
  const int wc = (wave & 1) * 64;
  const int m0 = blockIdx.y * 128;
  const int n0 = blockIdx.x * 128;
  const int lda = 1024, ldb = 1024, K = 1024;

  f32x4 acc[4][4] = {};

  const int r0 = tid >> 2;
  const int q8 = (tid & 3) * 8;
  const uint16_t* gA0 = A + (size_t)(m0 + r0) * lda + q8;
  const uint16_t* gA1 = A + (size_t)(m0 + 64 + r0) * lda + q8;
  const uint16_t* gB0 = Bt + (size_t)(n0 + r0) * ldb + q8;
  const uint16_t* gB1 = Bt + (size_t)(n0 + 64 + r0) * ldb + q8;
  uint16_t* lA0 = As + wave * 512;
  uint16_t* lA1 = As + 2048 + wave * 512;
  uint16_t* lB0 = Bs + wave * 512;
  uint16_t* lB1 = Bs + 2048 + wave * 512;

  const int fr = lane & 15;
  const int rg = lane >> 4;
  const int kq = rg * 8;

  for (int k0 = 0; k0 < K; k0 += 32) {
    __syncthreads();
    gload16(gA0 + k0, lA0);
    gload16(gA1 + k0, lA1);
    gload16(gB0 + k0, lB0);
    gload16(gB1 + k0, lB1);
    __syncthreads();

    bf16x8 a[4], b[4];
#pragma unroll
    for (int i = 0; i < 4; ++i)
      a[i] = *(const bf16x8*)(As + (wr + i * 16 + fr) * 32 + kq);
#pragma unroll
    for (int j = 0; j < 4; ++j)
      b[j] = *(const bf16x8*)(Bs + (wc + j * 16 + fr) * 32 + kq);
#pragma unroll
    for (int i = 0; i < 4; ++i)
#pragma unroll
      for (int j = 0; j < 4; ++j)
        acc[i][j] = __builtin_amdgcn_mfma_f32_16x16x32_bf16(a[i], b[j], acc[i][j], 0, 0, 0);
  }

  // C/D layout: col = lane&15, row = rg*4 + reg   [m89-verified]
  if (n0 < 2048) {
    // vT (transposed store). Arena [16 n-rows][64 m + pad] stride 72.
    __syncthreads();
    uint16_t* ar = SH + wave * 2048;
    const int lrow = lane >> 3;
    const int mc = (lane & 7) * 8;
#pragma unroll
    for (int j = 0; j < 4; ++j) {
      const float bc = p.bias[n0 + wc + j * 16 + fr];
#pragma unroll
      for (int i = 0; i < 4; ++i)
#pragma unroll
        for (int r = 0; r < 4; ++r)
          ar[fr * 72 + i * 16 + rg * 4 + r] = f2bf(silu_f(acc[i][j][r] + bc));
#pragma unroll
      for (int rr = 0; rr < 2; ++rr) {
        bf16x8 v = *(const bf16x8*)(ar + (rr * 8 + lrow) * 72 + mc);
        *(bf16x8*)(p.o16a + (size_t)(n0 + wc + j * 16 + rr * 8 + lrow) * 8192 + m0 + wr + mc) = v;
      }
    }
  } else if (n0 < 4096) {
    // gate. Arena [16 m-rows][64 n + pad] stride 72.
    __syncthreads();
    uint16_t* ar = SH + wave * 2048;
    const int lrow = lane >> 3;
    const int nc = (lane & 7) * 8;
    float bc[4];
#pragma unroll
    for (int j = 0; j < 4; ++j) bc[j] = p.bias[n0 + wc + j * 16 + fr];
#pragma unroll
    for (int i = 0; i < 4; ++i) {
#pragma unroll
      for (int j = 0; j < 4; ++j)
#pragma unroll
        for (int r = 0; r < 4; ++r)
          ar[(rg * 4 + r) * 72 + j * 16 + fr] = f2bf(silu_f(acc[i][j][r] + bc[j]));
#pragma unroll
      for (int rr = 0; rr < 2; ++rr) {
        bf16x8 v = *(const bf16x8*)(ar + (rr * 8 + lrow) * 72 + nc);
        *(bf16x8*)(p.o16b + (size_t)(m0 + wr + i * 16 + rr * 8 + lrow) * 2048 + (n0 - 2048) + wc + nc) = v;
      }
    }
  } else {
    // q,k: stride 224, cols 200..223 forced zero.
#pragma unroll
    for (int i = 0; i < 4; ++i) {
#pragma unroll
      for (int j = 0; j < 4; ++j) {
        const int row = m0 + wr + i * 16 + rg * 4;
        const int qc = n0 + wc + j * 16 + fr - 4096;   // 0..255
        if (qc < 224) {
#pragma unroll
          for (int r = 0; r < 4; ++r) {
            float qv = 0.f, kv = 0.f;
            if (qc < 200) {
              float s = silu_f(acc[i][j][r] + p.bias2[qc]);
              qv = s * p.g0[qc] + p.b0[qc];
              kv = s * p.g1[qc] + p.b1[qc];
            }
            p.oq[(size_t)(row + r) * 224 + qc] = f2bf(qv);
            p.ok[(size_t)(row + r) * 224 + qc] = f2bf(kv);
          }
        }
      }
    }
  }
}

// ---------------------------------------------------------------------------
// k_attn: attn = relu(q@kT/32)^2, K=224, 128x128 tile (R5 structure, ~34 KB
// LDS -> 4 blocks/CU). Coalesced bounce epilogue: per-wave dbuf arena,
// 2x16B stores per lane.
// ---------------------------------------------------------------------------
__global__ __launch_bounds__(256) void k_attn(
    const uint16_t* __restrict__ Q,
    const uint16_t* __restrict__ Kt,
    uint16_t* __restrict__ attn) {
  __shared__ __align__(16) uint16_t As[128 * 32];
  __shared__ __align__(16) uint16_t Bs[128 * 32];
  __shared__ __align__(16) uint16_t Ep[4][2][16 * 72];   // 18.4 KB, per-wave dbuf

  const int tid = threadIdx.x;
  const int lane = tid & 63;
  const int wave = tid >> 6;
  const int wr = (wave >> 1) * 64;
  const int wc = (wave & 1) * 64;
  const int m0 = blockIdx.y * 128;
  const int n0 = blockIdx.x * 128;
  const int lda = 224, ldb = 224, K = 224;

  f32x4 acc[4][4] = {};

  const int r0 = tid >> 2;
  const int q8 = (tid & 3) * 8;
  const uint16_t* gA0 = Q + (size_t)(m0 + r0) * lda + q8;
  const uint16_t* gA1 = Q + (size_t)(m0 + 64 + r0) * lda + q8;
  const uint16_t* gB0 = Kt + (size_t)(n0 + r0) * ldb + q8;
  const uint16_t* gB1 = Kt + (size_t)(n0 + 64 + r0) * ldb + q8;
  uint16_t* lA0 = As + wave * 512;
  uint16_t* lA1 = As + 2048 + wave * 512;
  uint16_t* lB0 = Bs + wave * 512;
  uint16_t* lB1 = Bs + 2048 + wave * 512;

  const int fr = lane & 15;
  const int rg = lane >> 4;
  const int kq = rg * 8;

  for (int k0 = 0; k0 < K; k0 += 32) {
    __syncthreads();
    gload16(gA0 + k0, lA0);
    gload16(gA1 + k0, lA1);
    gload16(gB0 + k0, lB0);
    gload16(gB1 + k0, lB1);
    __syncthreads();

    bf16x8 a[4], b[4];
#pragma unroll
    for (int i = 0; i < 4; ++i)
      a[i] = *(const bf16x8*)(As + (wr + i * 16 + fr) * 32 + kq);
#pragma unroll
    for (int j = 0; j < 4; ++j)
      b[j] = *(const bf16x8*)(Bs + (wc + j * 16 + fr) * 32 + kq);
#pragma unroll
    for (int i = 0; i < 4; ++i)
#pragma unroll
      for (int j = 0; j < 4; ++j)
        acc[i][j] = __builtin_amdgcn_mfma_f32_16x16x32_bf16(a[i], b[j], acc[i][j], 0, 0, 0);
  }

  // bounce epilogue: per i, wave-local [16 rows][64 cols] stride 72
#pragma unroll
  for (int i = 0; i < 4; ++i) {
    uint16_t* sl = Ep[wave][i & 1];
#pragma unroll
    for (int j = 0; j < 4; ++j)
#pragma unroll
      for (int r = 0; r < 4; ++r) {
        float s = fmaxf(acc[i][j][r] * 0.03125f, 0.f);
        sl[(rg * 4 + r) * 72 + j * 16 + fr] = f2bf(s * s);
      }
    const int row = lane >> 2;
    const int c0 = (lane & 3) * 16;
    bf16x8 v0 = *(const bf16x8*)(sl + row * 72 + c0);
    bf16x8 v1 = *(const bf16x8*)(sl + row * 72 + c0 + 8);
    uint16_t* dst = attn + (size_t)(m0 + wr + i * 16 + row) * 8192 + (n0 + wc + c0);
    *(bf16x8*)(dst) = v0;
    *(bf16x8*)(dst + 8) = v1;
  }
}

// ---------------------------------------------------------------------------
// k_pv: out2 = (attn@v)*gate. 128(M) x 256(N), 512 thr, XCD swizzle.
// K-loop frozen (m97 plateau). Epilogue: LDS bounce, 16B gate loads + stores.
// ---------------------------------------------------------------------------
__global__ __launch_bounds__(512) void k_pv(
    const uint16_t* __restrict__ A, int lda,
    const uint16_t* __restrict__ Bt, int ldb,
    int K, int nx, EpiParams p) {
  __shared__ __align__(16) uint16_t SH[(128 + 256) * 32];   // As | Bs, 24 KB
  uint16_t* As = SH;
  uint16_t* Bs = SH + 4096;

  const int id = blockIdx.x;
  const int bx = (id >> 3) % nx;
  const int by = (id & 7) + 8 * (id / (8 * nx));
  const int m0 = by * 128;
  const int n0 = bx * 256;

  const int tid = threadIdx.x;
  const int lane = tid & 63;
  const int wave = tid >> 6;
  const int wr = (wave & 1) * 64;
  const int wc = (wave >> 1) * 64;

  f32x4 acc[4][4] = {};

  const int r0 = tid >> 2;
  const int q8 = (tid & 3) * 8;
  const uint16_t* gA  = A  + (size_t)(m0 + r0) * lda + q8;
  const uint16_t* gB0 = Bt + (size_t)(n0 + r0) * ldb + q8;
  const uint16_t* gB1 = Bt + (size_t)(n0 + 128 + r0) * ldb + q8;
  uint16_t* lA  = As + wave * 512;
  uint16_t* lB0 = Bs + wave * 512;
  uint16_t* lB1 = Bs + 4096 + wave * 512;

  const int fr = lane & 15;
  const int rg = lane >> 4;
  const int kq = rg * 8;

  for (int k0 = 0; k0 < K; k0 += 32) {
    __syncthreads();
    gload16(gA + k0, lA);
    gload16(gB0 + k0, lB0);
    gload16(gB1 + k0, lB1);
    __syncthreads();

    bf16x8 a[4], b[4];
#pragma unroll
    for (int i = 0; i < 4; ++i)
      a[i] = *(const bf16x8*)(As + (wr + i * 16 + fr) * 32 + kq);
#pragma unroll
    for (int j = 0; j < 4; ++j)
      b[j] = *(const bf16x8*)(Bs + (wc + j * 16 + fr) * 32 + kq);
#pragma unroll
    for (int i = 0; i < 4; ++i)
#pragma unroll
      for (int j = 0; j < 4; ++j)
        acc[i][j] = __builtin_amdgcn_mfma_f32_16x16x32_bf16(a[i], b[j], acc[i][j], 0, 0, 0);
  }

  __syncthreads();                         // reuse SH as arena
  uint16_t* ar = SH + wave * 1536;         // [16][72], 1152 used
  const int lrow = lane >> 3;
  const int nc = (lane & 7) * 8;
#pragma unroll
  for (int i = 0; i < 4; ++i) {
#pragma unroll
    for (int j = 0; j < 4; ++j)
#pragma unroll
      for (int r = 0; r < 4; ++r)
        ar[(rg * 4 + r) * 72 + j * 16 + fr] = f2bf(acc[i][j][r]);
#pragma unroll
    for (int rr = 0; rr < 2; ++rr) {
      const size_t base = (size_t)(m0 + wr + i * 16 + rr * 8 + lrow) * 2048 + n0 + wc + nc;
      bf16x8 v = *(const bf16x8*)(ar + (rr * 8 + lrow) * 72 + nc);
      bf16x8 g = *(const bf16x8*)(p.gate + base);
      bf16x8 o;
#pragma unroll
      for (int e = 0; e < 8; ++e) o[e] = (__bf16)((float)v[e] * (float)g[e]);
      *(bf16x8*)(p.o16a + base) = o;
    }
  }
}

// ---------------------------------------------------------------------------
// k_final: y = (out2g@WoT^T + bo) * x, fp32 out. 128x128, K=2048.
// ---------------------------------------------------------------------------
__global__ __launch_bounds__(256) void k_final(
    const uint16_t* __restrict__ A,
    const uint16_t* __restrict__ Bt, EpiParams p) {
  __shared__ __align__(16) uint16_t As[128 * 32];
  __shared__ __align__(16) uint16_t Bs[128 * 32];

  const int tid = threadIdx.x;
  const int lane = tid & 63;
  const int wave = tid >> 6;
  const int wr = (wave >> 1) * 64;
  const int wc = (wave & 1) * 64;
  const int m0 = blockIdx.y * 128;
  const int n0 = blockIdx.x * 128;
  const int lda = 2048, ldb = 2048, K = 2048;

  f32x4 acc[4][4] = {};

  const int r0 = tid >> 2;
  const int q8 = (tid & 3) * 8;
  const uint16_t* gA0 = A + (size_t)(m0 + r0) * lda + q8;
  const uint16_t* gA1 = A + (size_t)(m0 + 64 + r0) * lda + q8;
  const uint16_t* gB0 = Bt + (size_t)(n0 + r0) * ldb + q8;
  const uint16_t* gB1 = Bt + (size_t)(n0 + 64 + r0) * ldb + q8;
  uint16_t* lA0 = As + wave * 512;
  uint16_t* lA1 = As + 2048 + wave * 512;
  uint16_t* lB0 = Bs + wave * 512;
  uint16_t* lB1 = Bs + 2048 + wave * 512;

  const int fr = lane & 15;
  const int kq = (lane >> 4) * 8;

  for (int k0 = 0; k0 < K; k0 += 32) {
    __syncthreads();
    gload16(gA0 + k0, lA0);
    gload16(gA1 + k0, lA1);
    gload16(gB0 + k0, lB0);
    gload16(gB1 + k0, lB1);
    __syncthreads();

    bf16x8 a[4], b[4];
#pragma unroll
    for (int i = 0; i < 4; ++i)
      a[i] = *(const bf16x8*)(As + (wr + i * 16 + fr) * 32 + kq);
#pragma unroll
    for (int j = 0; j < 4; ++j)
      b[j] = *(const bf16x8*)(Bs + (wc + j * 16 + fr) * 32 + kq);
#pragma unroll
    for (int i = 0; i < 4; ++i)
#pragma unroll
      for (int j = 0; j < 4; ++j)
        acc[i][j] = __builtin_amdgcn_mfma_f32_16x16x32_bf16(a[i], b[j], acc[i][j], 0, 0, 0);
  }

#pragma unroll
  for (int i = 0; i < 4; ++i) {
#pragma unroll
    for (int j = 0; j < 4; ++j) {
      const int row = m0 + wr + i * 16 + (lane >> 4) * 4;
      const int col = n0 + wc + j * 16 + fr;
      const float bc = p.bias[col];
#pragma unroll
      for (int r = 0; r < 4; ++r) {
        size_t idx = (size_t)(row + r) * 1024 + col;
        p.o32[idx] = (acc[i][j][r] + bc) * p.x[idx];
      }
    }
  }
}

// ---------------- launch ----------------

extern "C" void kernel_launch(void* const* d_in, const int* in_sizes, int n_in,
                              void* d_out, int out_size, void* d_ws, size_t ws_size,
                              hipStream_t stream) {
  const float* x        = (const float*)d_in[0];
  const float* W_hidden = (const float*)d_in[1];
  const float* b_hidden = (const float*)d_in[2];
  const float* W_qk     = (const float*)d_in[3];
  const float* b_qk     = (const float*)d_in[4];
  const float* gamma    = (const float*)d_in[5];
  const float* beta     = (const float*)d_in[6];
  const float* W_out    = (const float*)d_in[7];
  const float* b_out    = (const float*)d_in[8];
  float* out = (float*)d_out;

  const bool fullM = ws_size >= (236ull << 20);
  const size_t region0 = fullM ? (128ull << 20) : (64ull << 20);

  char* base = (char*)d_ws;
  uint16_t* xb    = (uint16_t*)(base);                         // 16 MB  [8192][1024]
  uint16_t* WhT   = (uint16_t*)(base + (16ull << 20));         //  8 MB  [4096][1024]
  uint16_t* WqkT  = (uint16_t*)(base + (24ull << 20));         // .5 MB  [256][1024]
  uint16_t* attnB = (uint16_t*)(base);                         // 64/128 MB
  char* tail = base + region0;
  uint16_t* WoT   = (uint16_t*)(tail);                         //  4 MB  [1024][2048]
  uint16_t* q     = (uint16_t*)(tail + (4ull << 20));          // 3.5 MB [8192][224]
  uint16_t* kk    = (uint16_t*)(tail + (8ull << 20));          // 3.5 MB
  uint16_t* vT    = (uint16_t*)(tail + (12ull << 20));         // 32 MB  [2048][8192]
  uint16_t* gate  = (uint16_t*)(tail + (44ull << 20));         // 32 MB  [8192][2048]
  uint16_t* out2g = (uint16_t*)(tail + (76ull << 20));         // 32 MB  [8192][2048]
  (void)in_sizes; (void)n_in; (void)out_size;

  // prep
  cast_to_bf16<<<(8192 * 1024 / 4) / 256, 256, 0, stream>>>(x, xb, 8192 * 1024 / 4);
  transpose_cast_pad<<<dim3(4096 / 32, 1024 / 32), dim3(32, 8), 0, stream>>>(W_hidden, WhT, 1024, 4096, 4096);
  transpose_cast_pad<<<dim3(256 / 32, 1024 / 32), dim3(32, 8), 0, stream>>>(W_qk, WqkT, 1024, 200, 256);
  transpose_cast_pad<<<dim3(1024 / 32, 2048 / 32), dim3(32, 8), 0, stream>>>(W_out, WoT, 2048, 1024, 1024);

  // fused hid + qk   (N = 4096 + 256 = 4352)
  {
    EpiParams p{};
    p.bias = b_hidden; p.bias2 = b_qk;
    p.g0 = gamma; p.b0 = beta; p.g1 = gamma + 200; p.b1 = beta + 200;
    p.o16a = vT; p.o16b = gate; p.oq = q; p.ok = kk;
    k_hidqk<<<dim3(34, 64), 256, 0, stream>>>(xb, WhT, p);
  }

  if (fullM) {
    k_attn<<<dim3(64, 64), 256, 0, stream>>>(q, kk, attnB);
    {
      EpiParams p{};
      p.gate = gate; p.o16a = out2g;
      k_pv<<<dim3(8 * 64), 512, 0, stream>>>(attnB, 8192, vT, 8192, 8192, 8, p);
    }
  } else {
    for (int s = 0; s < 2; ++s) {
      k_attn<<<dim3(64, 32), 256, 0, stream>>>(q + (size_t)s * 4096 * 224, kk, attnB);
      {
        EpiParams p{};
        p.gate = gate + (size_t)s * 4096 * 2048;
        p.o16a = out2g + (size_t)s * 4096 * 2048;
        k_pv<<<dim3(8 * 32), 512, 0, stream>>>(attnB, 8192, vT, 8192, 8192, 8, p);
      }
    }
  }

  // y = (out2g@Wo + bo) * x
  {
    EpiParams p{};
    p.bias = b_out; p.x = x; p.o32 = out;
    k_final<<<dim3(8, 64), 256, 0, stream>>>(out2g, WoT, p);
  }
}